// Round 10
// baseline (312.337 us; speedup 1.0000x reference)
//
#include <hip/hip_runtime.h>
#include <math.h>

constexpr int N = 50000;   // nodes
constexpr int E = 800000;  // edges (without self-loops)
constexpr int F = 128;     // features / hidden
constexpr int G = 256;     // graphs
constexpr int T = 4;       // tasks

constexpr int SCAN_B = 256;
constexpr int NBLK = (N + SCAN_B - 1) / SCAN_B;  // 196

// k_pre block-range layout
constexpr int WC_BLKS  = (F * F + 255) / 256;    // 64
constexpr int DEG_BLKS = (E + 255) / 256;        // 3125
constexpr int SUM_BLKS = (G * F + 255) / 256;    // 128
constexpr int PRE_DEG0 = 2 * WC_BLKS + 1;        // 129
constexpr int PRE_SUM0 = PRE_DEG0 + DEG_BLKS;    // 3254
constexpr int PRE_BLKS = PRE_SUM0 + SUM_BLKS;    // 3382

constexpr int GB1 = (N + 63) / 64;               // 782 gemm blocks

typedef __attribute__((ext_vector_type(8))) short short8;
typedef __attribute__((ext_vector_type(4))) float floatx4;

// bf16 <-> fp32 helpers (RNE on pack; values are finite)
__device__ inline float bf2f(unsigned short u) {
    union { unsigned int i; float f; } v;
    v.i = ((unsigned int)u) << 16;
    return v.f;
}
__device__ inline unsigned short f2bf(float f) {
    union { float f; unsigned int i; } v;
    v.f = f;
    unsigned int r = v.i + 0x7FFF + ((v.i >> 16) & 1);
    return (unsigned short)(r >> 16);
}
__device__ inline unsigned int pack2bf(float a, float b) {
    return (unsigned int)f2bf(a) | ((unsigned int)f2bf(b) << 16);
}

// pack W (fp32) -> MFMA-B-fragment order, hi/lo bf16 split
__device__ inline void wcast_one(const float* __restrict__ W,
                                 unsigned short* __restrict__ Whi,
                                 unsigned short* __restrict__ Wlo, int i) {
    if (i >= F * F) return;
    int k = i >> 7, n = i & 127;
    float w = W[i];
    unsigned short hi = f2bf(w);
    unsigned short lo = f2bf(w - bf2f(hi));
    int s = k >> 5, q = (k >> 3) & 3, j = k & 7;
    int idx = (((s * 128 + n) * 4 + q) * 8) + j;
    Whi[idx] = hi;
    Wlo[idx] = lo;
}

// ---------------- fused preamble: wcast(W1), wcast(W2), cntbs, deg8 hist, zero(sums) ----------------
__global__ __launch_bounds__(256) void k_pre(const float* __restrict__ W1, const float* __restrict__ W2,
                                             unsigned short* __restrict__ w1h, unsigned short* __restrict__ w1l,
                                             unsigned short* __restrict__ w2h, unsigned short* __restrict__ w2l,
                                             const int* __restrict__ dst, int* __restrict__ deg8,
                                             const int* __restrict__ batch, float* __restrict__ cnt,
                                             float* __restrict__ sums) {
    int b = blockIdx.x, t = threadIdx.x;
    if (b < WC_BLKS) {
        wcast_one(W1, w1h, w1l, b * 256 + t);
    } else if (b < 2 * WC_BLKS) {
        wcast_one(W2, w2h, w2l, (b - WC_BLKS) * 256 + t);
    } else if (b == 2 * WC_BLKS) {
        int g = t;
        int lo0 = 0, hi0 = N;
        while (lo0 < hi0) { int m = (lo0 + hi0) >> 1; if (batch[m] < g) lo0 = m + 1; else hi0 = m; }
        int lo1 = lo0, hi1 = N;
        while (lo1 < hi1) { int m = (lo1 + hi1) >> 1; if (batch[m] < g + 1) lo1 = m + 1; else hi1 = m; }
        cnt[g] = (float)(lo1 - lo0);
    } else if (b < PRE_SUM0) {
        int chunk = b - PRE_DEG0;
        int e = chunk * 256 + t;
        if (e < E) atomicAdd(&deg8[(chunk & 7) * N + dst[e]], 1);
    } else {
        int i = (b - PRE_SUM0) * 256 + t;
        if (i < G * F) sums[i] = 0.f;
    }
}

// ---------------- two-level scan: sum deg8 copies, block partials + dinv ----------------
__global__ __launch_bounds__(SCAN_B) void k_part(const int* __restrict__ deg8,
                                                 int* __restrict__ deg,
                                                 int* __restrict__ part,
                                                 float* __restrict__ dinv) {
    __shared__ int s[SCAN_B];
    int t = threadIdx.x;
    int i = blockIdx.x * SCAN_B + t;
    int v = 0;
    if (i < N) {
#pragma unroll
        for (int c = 0; c < 8; ++c) v += deg8[c * N + i];
        deg[i] = v;
        dinv[i] = rsqrtf((float)(v + 1));  // +1 self-loop
    }
    s[t] = v;
    __syncthreads();
#pragma unroll
    for (int off = SCAN_B / 2; off > 0; off >>= 1) {
        if (t < off) s[t] += s[t + off];
        __syncthreads();
    }
    if (t == 0) part[blockIdx.x] = s[0];
}

// ---------------- scan the 196 partials (exclusive) ----------------
__global__ __launch_bounds__(SCAN_B) void k_scanpart(int* __restrict__ part) {
    __shared__ int s[SCAN_B];
    int t = threadIdx.x;
    int v = (t < NBLK) ? part[t] : 0;
    s[t] = v;
    __syncthreads();
    for (int off = 1; off < SCAN_B; off <<= 1) {
        int u = (t >= off) ? s[t - off] : 0;
        __syncthreads();
        s[t] += u;
        __syncthreads();
    }
    if (t < NBLK) part[t] = s[t] - v;  // exclusive prefix of block sums
}

// ---------------- per-block scan + offset -> rowstart + class-split fillpos8 ----------------
__global__ __launch_bounds__(SCAN_B) void k_rowfill(const int* __restrict__ deg,
                                                    const int* __restrict__ deg8,
                                                    const int* __restrict__ part,
                                                    int* __restrict__ rowstart,
                                                    int* __restrict__ fillpos8) {
    __shared__ int s[SCAN_B];
    int t = threadIdx.x;
    int i = blockIdx.x * SCAN_B + t;
    int v = (i < N) ? deg[i] : 0;
    s[t] = v;
    __syncthreads();
    for (int off = 1; off < SCAN_B; off <<= 1) {
        int u = (t >= off) ? s[t - off] : 0;
        __syncthreads();
        s[t] += u;
        __syncthreads();
    }
    int excl = s[t] - v + part[blockIdx.x];
    if (i < N) {
        rowstart[i] = excl;
        int run = excl;
#pragma unroll
        for (int c = 0; c < 8; ++c) {        // disjoint per-class sub-ranges
            fillpos8[c * N + i] = run;
            run += deg8[c * N + i];
        }
    }
    if (blockIdx.x == 0 && t == 0) rowstart[N] = E;  // total degree == E
}

// ---------------- MFMA GEMM body: C16[64,128](bf16) = dinv[row] * (A-tile @ W) ----------------
// Output rows pre-scaled by dinv so agg's per-edge coefficient becomes 1
// (csr stores src only; agg scales by dinv[d] once at the end).
template <bool ABF16>
__device__ __forceinline__ void gemm_body(const void* __restrict__ Ain,
                                          const unsigned short* __restrict__ Wph,
                                          const unsigned short* __restrict__ Wpl,
                                          const float* __restrict__ dinv,
                                          unsigned short* __restrict__ C16,
                                          int row0, int tid) {
    __shared__ __align__(16) unsigned short Albs[64 * 136];  // row-major, pad 136

    if (ABF16) {
        const uint4* A8 = (const uint4*)Ain;              // 16 uint4 per row
        for (int f = tid; f < 64 * 16; f += 256) {
            int r = f >> 4, kq = f & 15;
            int row = row0 + r;
            uint4 v = make_uint4(0u, 0u, 0u, 0u);
            if (row < N) v = A8[row * 16 + kq];
            *(uint4*)&Albs[r * 136 + kq * 8] = v;
        }
    } else {
        const float4* A4 = (const float4*)Ain;
        for (int f = tid; f < 64 * 32; f += 256) {
            int r = f >> 5, kq = f & 31;
            int row = row0 + r;
            float4 v = make_float4(0.f, 0.f, 0.f, 0.f);
            if (row < N) v = A4[row * 32 + kq];
            ushort4 o;
            o.x = f2bf(v.x); o.y = f2bf(v.y); o.z = f2bf(v.z); o.w = f2bf(v.w);
            *(ushort4*)&Albs[r * 136 + kq * 4] = o;
        }
    }
    __syncthreads();

    int wv = tid >> 6;        // wave 0..3 -> rows wv*16..wv*16+15
    int lane = tid & 63;
    int c16 = lane & 15;
    int q = lane >> 4;        // 0..3
    int m = wv * 16 + c16;

    floatx4 acc[8];
#pragma unroll
    for (int nt = 0; nt < 8; ++nt) acc[nt] = (floatx4){0.f, 0.f, 0.f, 0.f};

    const short8* WH = (const short8*)Wph;
    const short8* WL = (const short8*)Wpl;
#pragma unroll
    for (int s = 0; s < 4; ++s) {
        short8 a = *(const short8*)&Albs[m * 136 + s * 32 + q * 8];
        int wb = s * 512 + c16 * 4 + q;  // short8 units
#pragma unroll
        for (int nt = 0; nt < 8; ++nt) {
            acc[nt] = __builtin_amdgcn_mfma_f32_16x16x32_bf16(a, WH[wb + nt * 64], acc[nt], 0, 0, 0);
            acc[nt] = __builtin_amdgcn_mfma_f32_16x16x32_bf16(a, WL[wb + nt * 64], acc[nt], 0, 0, 0);
        }
    }

    // C/D layout: col = lane&15, row = (lane>>4)*4 + reg
    int rbase = row0 + wv * 16 + q * 4;
#pragma unroll
    for (int r = 0; r < 4; ++r) {
        int row = rbase + r;
        if (row < N) {
            float dv = dinv[row];
#pragma unroll
            for (int nt = 0; nt < 8; ++nt)
                C16[row * 128 + nt * 16 + c16] = f2bf(acc[nt][r] * dv);
        }
    }
}

template <bool ABF16>
__global__ __launch_bounds__(256) void k_gemm(const void* __restrict__ Ain,
                                              const unsigned short* __restrict__ Wph,
                                              const unsigned short* __restrict__ Wpl,
                                              const float* __restrict__ dinv,
                                              unsigned short* __restrict__ C16) {
    gemm_body<ABF16>(Ain, Wph, Wpl, dinv, C16, blockIdx.x * 64, threadIdx.x);
}

// ---------------- fused: gemm1 (blocks 0..GB1) + full-lane class-split CSR fill ----------------
// csr entry is src only (4B); stores are non-temporal to skip cross-XCD L2
// line ownership ping-pong on the random scatter.
__global__ __launch_bounds__(256) void k_fillgemm(const float* __restrict__ x,
                                                  const unsigned short* __restrict__ w1h,
                                                  const unsigned short* __restrict__ w1l,
                                                  const float* __restrict__ dinv,
                                                  unsigned short* __restrict__ tmp16,
                                                  const int* __restrict__ src,
                                                  const int* __restrict__ dst,
                                                  int* __restrict__ fillpos8,
                                                  int* __restrict__ csr) {
    int b = blockIdx.x;
    if (b < GB1) {
        gemm_body<false>(x, w1h, w1l, dinv, tmp16, b * 64, threadIdx.x);
        return;
    }
    int chunk = b - GB1;                    // 0..DEG_BLKS-1
    int e = chunk * 256 + threadIdx.x;
    if (e >= E) return;
    int d = dst[e];
    int s = src[e];
    int pos = atomicAdd(&fillpos8[(chunk & 7) * N + d], 1);
    __builtin_nontemporal_store(s, &csr[pos]);
}

// 8 bf16 (uint4) fma into 8 fp32 accumulators
__device__ inline void fma8(const uint4& u, float c, float* acc) {
    union { unsigned int i; float f; } a;
    a.i = u.x << 16;          acc[0] = fmaf(a.f, c, acc[0]);
    a.i = u.x & 0xFFFF0000u;  acc[1] = fmaf(a.f, c, acc[1]);
    a.i = u.y << 16;          acc[2] = fmaf(a.f, c, acc[2]);
    a.i = u.y & 0xFFFF0000u;  acc[3] = fmaf(a.f, c, acc[3]);
    a.i = u.z << 16;          acc[4] = fmaf(a.f, c, acc[4]);
    a.i = u.z & 0xFFFF0000u;  acc[5] = fmaf(a.f, c, acc[5]);
    a.i = u.w << 16;          acc[6] = fmaf(a.f, c, acc[6]);
    a.i = u.w & 0xFFFF0000u;  acc[7] = fmaf(a.f, c, acc[7]);
}

// ---------------- gather aggregation (pre-scaled bf16 msgs, 16 lanes/row) ----------------
// acc = Sum h'[s] + h'[node]; out = relu(dinv[node]*acc + bias)
__global__ __launch_bounds__(256) void k_agg(const unsigned short* __restrict__ tmp16,
                                             const int* __restrict__ csr,
                                             const int* __restrict__ rowstart,
                                             const float* __restrict__ dinv,
                                             const float* __restrict__ bias,
                                             unsigned short* __restrict__ out16) {
    int node = (blockIdx.x * blockDim.x + threadIdx.x) >> 4;
    int lane = threadIdx.x & 15;           // 16 B per lane -> 256 B row
    if (node >= N) return;
    const uint4* t8 = (const uint4*)tmp16; // 16 uint4 per row
    float acc[8] = {0.f, 0.f, 0.f, 0.f, 0.f, 0.f, 0.f, 0.f};
    fma8(t8[node * 16 + lane], 1.0f, acc); // self term h'[node]

    int jb = rowstart[node], je = rowstart[node + 1];
    for (int j = jb; j < je; j += 8) {
        int e[8];
        float msk[8];
#pragma unroll
        for (int k = 0; k < 8; ++k) {
            int idx = j + k;
            e[k] = csr[idx < je ? idx : je - 1];  // clamp: dup gather hits cache
            msk[k] = (idx < je) ? 1.0f : 0.0f;
        }
        uint4 u[8];
#pragma unroll
        for (int k = 0; k < 8; ++k) u[k] = t8[e[k] * 16 + lane];
#pragma unroll
        for (int k = 0; k < 8; ++k) fma8(u[k], msk[k], acc);
    }

    float di = dinv[node];
    const float4* b4 = (const float4*)bias;
    float4 ba = b4[lane * 2], bb = b4[lane * 2 + 1];
    uint4 o;
    o.x = pack2bf(fmaxf(fmaf(acc[0], di, ba.x), 0.f), fmaxf(fmaf(acc[1], di, ba.y), 0.f));
    o.y = pack2bf(fmaxf(fmaf(acc[2], di, ba.z), 0.f), fmaxf(fmaf(acc[3], di, ba.w), 0.f));
    o.z = pack2bf(fmaxf(fmaf(acc[4], di, bb.x), 0.f), fmaxf(fmaf(acc[5], di, bb.y), 0.f));
    o.w = pack2bf(fmaxf(fmaf(acc[6], di, bb.z), 0.f), fmaxf(fmaf(acc[7], di, bb.w), 0.f));
    ((uint4*)out16)[node * 16 + lane] = o;
}

// ---------------- mean-pool accumulate over bf16 h (batch is sorted) ----------------
__global__ void k_pool(const unsigned short* __restrict__ h16, const int* __restrict__ batch,
                       float* __restrict__ sums) {
    int grp = (blockIdx.x * blockDim.x + threadIdx.x) >> 4;
    int lane = threadIdx.x & 15;
    int base = grp * 64;
    if (base >= N) return;
    int end = (base + 64 < N) ? base + 64 : N;
    float acc[8] = {0.f, 0.f, 0.f, 0.f, 0.f, 0.f, 0.f, 0.f};
    const uint4* h4 = (const uint4*)h16;
    int curb = batch[base];
    for (int i = base; i < end; ++i) {
        int b = batch[i];
        if (b != curb) {
            float* sp = &sums[curb * F + lane * 8];
#pragma unroll
            for (int k = 0; k < 8; ++k) { atomicAdd(sp + k, acc[k]); acc[k] = 0.f; }
            curb = b;
        }
        fma8(h4[i * 16 + lane], 1.0f, acc);
    }
    float* sp = &sums[curb * F + lane * 8];
#pragma unroll
    for (int k = 0; k < 8; ++k) atomicAdd(sp + k, acc[k]);
}

// ---------------- z = relu(pooled @ Wfc + bfc) ----------------
__global__ __launch_bounds__(128) void k_fc(const float* __restrict__ sums,
                                            const float* __restrict__ cnt,
                                            const float* __restrict__ Wfc,
                                            const float* __restrict__ bfc,
                                            float* __restrict__ z) {
    __shared__ float p[128];
    int g = blockIdx.x, t = threadIdx.x;
    float inv = 1.0f / fmaxf(cnt[g], 1.0f);
    p[t] = sums[g * F + t] * inv;
    __syncthreads();
    float acc = bfc[t];
    for (int k = 0; k < F; ++k) acc = fmaf(p[k], Wfc[k * F + t], acc);
    z[g * F + t] = fmaxf(acc, 0.f);
}

// ---------------- out[t,g,c] = z[g,:] . Wh[t,:,c] + bh[t,c] ----------------
__global__ void k_head(const float* __restrict__ z, const float* __restrict__ Wh,
                       const float* __restrict__ bh, float* __restrict__ out) {
    int o = blockIdx.x * blockDim.x + threadIdx.x;
    if (o >= T * G * 2) return;
    int tt = o >> 9;        // / (G*2)
    int rem = o & 511;
    int g = rem >> 1;
    int c = rem & 1;
    float acc = bh[tt * 2 + c];
    const float* zr = &z[g * F];
    const float* wr = &Wh[tt * F * 2 + c];
    for (int h = 0; h < F; ++h) acc = fmaf(zr[h], wr[h * 2], acc);
    out[o] = acc;
}

extern "C" void kernel_launch(void* const* d_in, const int* in_sizes, int n_in,
                              void* d_out, int out_size, void* d_ws, size_t ws_size,
                              hipStream_t stream) {
    const float* x    = (const float*)d_in[0];
    const int*   ei   = (const int*)d_in[1];      // [2,E]: row0=src, row1=dst
    const int*   batch= (const int*)d_in[2];
    const float* W1   = (const float*)d_in[3];
    const float* b1   = (const float*)d_in[4];
    const float* W2   = (const float*)d_in[5];
    const float* b2   = (const float*)d_in[6];
    const float* Wfc  = (const float*)d_in[7];
    const float* bfc  = (const float*)d_in[8];
    const float* Wh   = (const float*)d_in[9];
    const float* bh   = (const float*)d_in[10];
    float* out = (float*)d_out;

    const int* srcp = ei;
    const int* dstp = ei + E;

    char* w = (char*)d_ws;
    auto alloc = [&](size_t bytes) {
        char* p = w;
        w += (bytes + 255) & ~(size_t)255;
        return p;
    };
    unsigned short* tmp16 = (unsigned short*)alloc((size_t)N * F * 2);
    unsigned short* hbuf16= (unsigned short*)alloc((size_t)N * F * 2);
    int*   csr      = (int*)  alloc((size_t)E * 4);
    int*   rowstart = (int*)  alloc((size_t)(N + 1) * 4);
    int*   fillpos8 = (int*)  alloc((size_t)8 * N * 4);
    int*   deg8     = (int*)  alloc((size_t)8 * N * 4);
    int*   deg      = (int*)  alloc((size_t)N * 4);
    float* dinv     = (float*)alloc((size_t)N * 4);
    int*   part     = (int*)  alloc((size_t)NBLK * 4);
    float* sums     = (float*)alloc((size_t)G * F * 4);
    float* cnt      = (float*)alloc((size_t)G * 4);
    float* z        = (float*)alloc((size_t)G * F * 4);
    unsigned short* w1h = (unsigned short*)alloc((size_t)F * F * 2);
    unsigned short* w1l = (unsigned short*)alloc((size_t)F * F * 2);
    unsigned short* w2h = (unsigned short*)alloc((size_t)F * F * 2);
    unsigned short* w2l = (unsigned short*)alloc((size_t)F * F * 2);

    hipMemsetAsync(deg8, 0, (size_t)8 * N * 4, stream);

    // fused preamble: wcast W1/W2, cntbs, 8-way deg histogram, zero sums
    k_pre<<<PRE_BLKS, 256, 0, stream>>>(W1, W2, w1h, w1l, w2h, w2l,
                                        dstp, deg8, batch, cnt, sums);

    // CSR build (two-level parallel scan; class-split fillpos8)
    k_part<<<NBLK, SCAN_B, 0, stream>>>(deg8, deg, part, dinv);
    k_scanpart<<<1, SCAN_B, 0, stream>>>(part);
    k_rowfill<<<NBLK, SCAN_B, 0, stream>>>(deg, deg8, part, rowstart, fillpos8);

    // fused: layer-1 GEMM (dinv-prescaled output) + 4B NT CSR fill
    k_fillgemm<<<GB1 + DEG_BLKS, 256, 0, stream>>>(x, w1h, w1l, dinv, tmp16,
                                                   srcp, dstp, fillpos8, csr);

    // layer 1 aggregation
    k_agg<<<(N * 16 + 255) / 256, 256, 0, stream>>>(tmp16, csr, rowstart, dinv, b1, hbuf16);
    // layer 2
    k_gemm<true><<<GB1, 256, 0, stream>>>(hbuf16, w2h, w2l, dinv, tmp16);
    k_agg<<<(N * 16 + 255) / 256, 256, 0, stream>>>(tmp16, csr, rowstart, dinv, b2, hbuf16);

    // pooling
    int ngrp = (N + 63) / 64;
    k_pool<<<(ngrp * 16 + 255) / 256, 256, 0, stream>>>(hbuf16, batch, sums);

    // fc + heads
    k_fc<<<G, 128, 0, stream>>>(sums, cnt, Wfc, bfc, z);
    k_head<<<(T * G * 2 + 255) / 256, 256, 0, stream>>>(z, Wh, bh, out);
}

// Round 11
// 284.621 us; speedup vs baseline: 1.0974x; 1.0974x over previous
//
#include <hip/hip_runtime.h>
#include <math.h>

constexpr int N = 50000;   // nodes
constexpr int E = 800000;  // edges (without self-loops)
constexpr int F = 128;     // features / hidden
constexpr int G = 256;     // graphs
constexpr int T = 4;       // tasks

constexpr int SCAN_B = 256;
constexpr int NBLK = (N + SCAN_B - 1) / SCAN_B;  // 196

// k_pre block-range layout
constexpr int WC_BLKS  = (F * F + 255) / 256;    // 64
constexpr int DEG_BLKS = (E + 255) / 256;        // 3125
constexpr int SUM_BLKS = (G * F + 255) / 256;    // 128
constexpr int PRE_DEG0 = 2 * WC_BLKS + 1;        // 129
constexpr int PRE_SUM0 = PRE_DEG0 + DEG_BLKS;    // 3254
constexpr int PRE_BLKS = PRE_SUM0 + SUM_BLKS;    // 3382

constexpr int GB1 = (N + 63) / 64;               // 782 gemm blocks
constexpr int AGB = N / 16;                      // 3125 fused agg+gemm blocks (16 | N)

typedef __attribute__((ext_vector_type(8))) short short8;
typedef __attribute__((ext_vector_type(4))) float floatx4;

// bf16 <-> fp32 helpers (RNE on pack; values are finite)
__device__ inline float bf2f(unsigned short u) {
    union { unsigned int i; float f; } v;
    v.i = ((unsigned int)u) << 16;
    return v.f;
}
__device__ inline unsigned short f2bf(float f) {
    union { float f; unsigned int i; } v;
    v.f = f;
    unsigned int r = v.i + 0x7FFF + ((v.i >> 16) & 1);
    return (unsigned short)(r >> 16);
}
__device__ inline unsigned int pack2bf(float a, float b) {
    return (unsigned int)f2bf(a) | ((unsigned int)f2bf(b) << 16);
}

// pack W (fp32) -> MFMA-B-fragment order, hi/lo bf16 split
__device__ inline void wcast_one(const float* __restrict__ W,
                                 unsigned short* __restrict__ Whi,
                                 unsigned short* __restrict__ Wlo, int i) {
    if (i >= F * F) return;
    int k = i >> 7, n = i & 127;
    float w = W[i];
    unsigned short hi = f2bf(w);
    unsigned short lo = f2bf(w - bf2f(hi));
    int s = k >> 5, q = (k >> 3) & 3, j = k & 7;
    int idx = (((s * 128 + n) * 4 + q) * 8) + j;
    Whi[idx] = hi;
    Wlo[idx] = lo;
}

// ---------------- fused preamble: wcast(W1), wcast(W2), cntbs, deg8 hist, zero(sums) ----------------
__global__ __launch_bounds__(256) void k_pre(const float* __restrict__ W1, const float* __restrict__ W2,
                                             unsigned short* __restrict__ w1h, unsigned short* __restrict__ w1l,
                                             unsigned short* __restrict__ w2h, unsigned short* __restrict__ w2l,
                                             const int* __restrict__ dst, int* __restrict__ deg8,
                                             const int* __restrict__ batch, float* __restrict__ cnt,
                                             float* __restrict__ sums) {
    int b = blockIdx.x, t = threadIdx.x;
    if (b < WC_BLKS) {
        wcast_one(W1, w1h, w1l, b * 256 + t);
    } else if (b < 2 * WC_BLKS) {
        wcast_one(W2, w2h, w2l, (b - WC_BLKS) * 256 + t);
    } else if (b == 2 * WC_BLKS) {
        int g = t;
        int lo0 = 0, hi0 = N;
        while (lo0 < hi0) { int m = (lo0 + hi0) >> 1; if (batch[m] < g) lo0 = m + 1; else hi0 = m; }
        int lo1 = lo0, hi1 = N;
        while (lo1 < hi1) { int m = (lo1 + hi1) >> 1; if (batch[m] < g + 1) lo1 = m + 1; else hi1 = m; }
        cnt[g] = (float)(lo1 - lo0);
    } else if (b < PRE_SUM0) {
        int chunk = b - PRE_DEG0;
        int e = chunk * 256 + t;
        if (e < E) atomicAdd(&deg8[(chunk & 7) * N + dst[e]], 1);
    } else {
        int i = (b - PRE_SUM0) * 256 + t;
        if (i < G * F) sums[i] = 0.f;
    }
}

// ---------------- two-level scan: sum deg8 copies, block partials + dinv ----------------
__global__ __launch_bounds__(SCAN_B) void k_part(const int* __restrict__ deg8,
                                                 int* __restrict__ deg,
                                                 int* __restrict__ part,
                                                 float* __restrict__ dinv) {
    __shared__ int s[SCAN_B];
    int t = threadIdx.x;
    int i = blockIdx.x * SCAN_B + t;
    int v = 0;
    if (i < N) {
#pragma unroll
        for (int c = 0; c < 8; ++c) v += deg8[c * N + i];
        deg[i] = v;
        dinv[i] = rsqrtf((float)(v + 1));  // +1 self-loop
    }
    s[t] = v;
    __syncthreads();
#pragma unroll
    for (int off = SCAN_B / 2; off > 0; off >>= 1) {
        if (t < off) s[t] += s[t + off];
        __syncthreads();
    }
    if (t == 0) part[blockIdx.x] = s[0];
}

// ---------------- scan the 196 partials (exclusive) ----------------
__global__ __launch_bounds__(SCAN_B) void k_scanpart(int* __restrict__ part) {
    __shared__ int s[SCAN_B];
    int t = threadIdx.x;
    int v = (t < NBLK) ? part[t] : 0;
    s[t] = v;
    __syncthreads();
    for (int off = 1; off < SCAN_B; off <<= 1) {
        int u = (t >= off) ? s[t - off] : 0;
        __syncthreads();
        s[t] += u;
        __syncthreads();
    }
    if (t < NBLK) part[t] = s[t] - v;  // exclusive prefix of block sums
}

// ---------------- per-block scan + offset -> rowstart + class-split fillpos8 ----------------
__global__ __launch_bounds__(SCAN_B) void k_rowfill(const int* __restrict__ deg,
                                                    const int* __restrict__ deg8,
                                                    const int* __restrict__ part,
                                                    int* __restrict__ rowstart,
                                                    int* __restrict__ fillpos8) {
    __shared__ int s[SCAN_B];
    int t = threadIdx.x;
    int i = blockIdx.x * SCAN_B + t;
    int v = (i < N) ? deg[i] : 0;
    s[t] = v;
    __syncthreads();
    for (int off = 1; off < SCAN_B; off <<= 1) {
        int u = (t >= off) ? s[t - off] : 0;
        __syncthreads();
        s[t] += u;
        __syncthreads();
    }
    int excl = s[t] - v + part[blockIdx.x];
    if (i < N) {
        rowstart[i] = excl;
        int run = excl;
#pragma unroll
        for (int c = 0; c < 8; ++c) {        // disjoint per-class sub-ranges
            fillpos8[c * N + i] = run;
            run += deg8[c * N + i];
        }
    }
    if (blockIdx.x == 0 && t == 0) rowstart[N] = E;  // total degree == E
}

// ---------------- MFMA GEMM body (64-row tile): C16 = dinv[row] * (A @ W) ----------------
template <bool ABF16>
__device__ __forceinline__ void gemm_body(const void* __restrict__ Ain,
                                          const unsigned short* __restrict__ Wph,
                                          const unsigned short* __restrict__ Wpl,
                                          const float* __restrict__ dinv,
                                          unsigned short* __restrict__ C16,
                                          int row0, int tid) {
    __shared__ __align__(16) unsigned short Albs[64 * 136];  // row-major, pad 136

    if (ABF16) {
        const uint4* A8 = (const uint4*)Ain;              // 16 uint4 per row
        for (int f = tid; f < 64 * 16; f += 256) {
            int r = f >> 4, kq = f & 15;
            int row = row0 + r;
            uint4 v = make_uint4(0u, 0u, 0u, 0u);
            if (row < N) v = A8[row * 16 + kq];
            *(uint4*)&Albs[r * 136 + kq * 8] = v;
        }
    } else {
        const float4* A4 = (const float4*)Ain;
        for (int f = tid; f < 64 * 32; f += 256) {
            int r = f >> 5, kq = f & 31;
            int row = row0 + r;
            float4 v = make_float4(0.f, 0.f, 0.f, 0.f);
            if (row < N) v = A4[row * 32 + kq];
            ushort4 o;
            o.x = f2bf(v.x); o.y = f2bf(v.y); o.z = f2bf(v.z); o.w = f2bf(v.w);
            *(ushort4*)&Albs[r * 136 + kq * 4] = o;
        }
    }
    __syncthreads();

    int wv = tid >> 6;        // wave 0..3 -> rows wv*16..wv*16+15
    int lane = tid & 63;
    int c16 = lane & 15;
    int q = lane >> 4;        // 0..3
    int m = wv * 16 + c16;

    floatx4 acc[8];
#pragma unroll
    for (int nt = 0; nt < 8; ++nt) acc[nt] = (floatx4){0.f, 0.f, 0.f, 0.f};

    const short8* WH = (const short8*)Wph;
    const short8* WL = (const short8*)Wpl;
#pragma unroll
    for (int s = 0; s < 4; ++s) {
        short8 a = *(const short8*)&Albs[m * 136 + s * 32 + q * 8];
        int wb = s * 512 + c16 * 4 + q;  // short8 units
#pragma unroll
        for (int nt = 0; nt < 8; ++nt) {
            acc[nt] = __builtin_amdgcn_mfma_f32_16x16x32_bf16(a, WH[wb + nt * 64], acc[nt], 0, 0, 0);
            acc[nt] = __builtin_amdgcn_mfma_f32_16x16x32_bf16(a, WL[wb + nt * 64], acc[nt], 0, 0, 0);
        }
    }

    // C/D layout: col = lane&15, row = (lane>>4)*4 + reg
    int rbase = row0 + wv * 16 + q * 4;
#pragma unroll
    for (int r = 0; r < 4; ++r) {
        int row = rbase + r;
        if (row < N) {
            float dv = dinv[row];
#pragma unroll
            for (int nt = 0; nt < 8; ++nt)
                C16[row * 128 + nt * 16 + c16] = f2bf(acc[nt][r] * dv);
        }
    }
}

// ---------------- fused: gemm1 (blocks 0..GB1) + full-lane class-split CSR fill ----------------
__global__ __launch_bounds__(256) void k_fillgemm(const float* __restrict__ x,
                                                  const unsigned short* __restrict__ w1h,
                                                  const unsigned short* __restrict__ w1l,
                                                  const float* __restrict__ dinv,
                                                  unsigned short* __restrict__ tmp16,
                                                  const int* __restrict__ src,
                                                  const int* __restrict__ dst,
                                                  int* __restrict__ fillpos8,
                                                  int* __restrict__ csr) {
    int b = blockIdx.x;
    if (b < GB1) {
        gemm_body<false>(x, w1h, w1l, dinv, tmp16, b * 64, threadIdx.x);
        return;
    }
    int chunk = b - GB1;                    // 0..DEG_BLKS-1
    int e = chunk * 256 + threadIdx.x;
    if (e >= E) return;
    int d = dst[e];
    int s = src[e];
    int pos = atomicAdd(&fillpos8[(chunk & 7) * N + d], 1);
    csr[pos] = s;                           // plain store: L2 write-combining > NT
}

// 8 bf16 (uint4) fma into 8 fp32 accumulators
__device__ inline void fma8(const uint4& u, float c, float* acc) {
    union { unsigned int i; float f; } a;
    a.i = u.x << 16;          acc[0] = fmaf(a.f, c, acc[0]);
    a.i = u.x & 0xFFFF0000u;  acc[1] = fmaf(a.f, c, acc[1]);
    a.i = u.y << 16;          acc[2] = fmaf(a.f, c, acc[2]);
    a.i = u.y & 0xFFFF0000u;  acc[3] = fmaf(a.f, c, acc[3]);
    a.i = u.z << 16;          acc[4] = fmaf(a.f, c, acc[4]);
    a.i = u.z & 0xFFFF0000u;  acc[5] = fmaf(a.f, c, acc[5]);
    a.i = u.w << 16;          acc[6] = fmaf(a.f, c, acc[6]);
    a.i = u.w & 0xFFFF0000u;  acc[7] = fmaf(a.f, c, acc[7]);
}

// agg inner loop: acc += Sum_{j in [jb,je)} tmp[csr[j]] (8-deep in flight)
__device__ __forceinline__ void agg_loop(const uint4* __restrict__ t8,
                                         const int* __restrict__ csr,
                                         int jb, int je, int lane, float* acc) {
    for (int j = jb; j < je; j += 8) {
        int e[8];
        float msk[8];
#pragma unroll
        for (int k = 0; k < 8; ++k) {
            int idx = j + k;
            e[k] = csr[idx < je ? idx : je - 1];  // clamp: dup gather hits cache
            msk[k] = (idx < je) ? 1.0f : 0.0f;
        }
        uint4 u[8];
#pragma unroll
        for (int k = 0; k < 8; ++k) u[k] = t8[e[k] * 16 + lane];
#pragma unroll
        for (int k = 0; k < 8; ++k) fma8(u[k], msk[k], acc);
    }
}

// ---------------- fused layer-1 agg + layer-2 GEMM (16 nodes/block) ----------------
// Phase A: aggregate h1 rows for 16 nodes, relu+bias, write bf16 into LDS A-tile.
// Phase B: 16-row MFMA tile -> tmp2 = dinv * (h1 @ W2). h1 never touches global.
__global__ __launch_bounds__(256) void k_agg1gemm(const unsigned short* __restrict__ tmp16,
                                                  const int* __restrict__ csr,
                                                  const int* __restrict__ rowstart,
                                                  const float* __restrict__ dinv,
                                                  const float* __restrict__ bias,
                                                  const unsigned short* __restrict__ w2h,
                                                  const unsigned short* __restrict__ w2l,
                                                  unsigned short* __restrict__ tmp2) {
    __shared__ __align__(16) unsigned short Albs[16 * 136];
    int tid = threadIdx.x;
    int row0 = blockIdx.x * 16;

    // ---- phase A: aggregation ----
    {
        int node = row0 + (tid >> 4);
        int lane = tid & 15;
        const uint4* t8 = (const uint4*)tmp16;
        float acc[8] = {0.f, 0.f, 0.f, 0.f, 0.f, 0.f, 0.f, 0.f};
        fma8(t8[node * 16 + lane], 1.0f, acc);   // self term h'[node]
        agg_loop(t8, csr, rowstart[node], rowstart[node + 1], lane, acc);

        float di = dinv[node];
        const float4* b4 = (const float4*)bias;
        float4 ba = b4[lane * 2], bb = b4[lane * 2 + 1];
        uint4 o;
        o.x = pack2bf(fmaxf(fmaf(acc[0], di, ba.x), 0.f), fmaxf(fmaf(acc[1], di, ba.y), 0.f));
        o.y = pack2bf(fmaxf(fmaf(acc[2], di, ba.z), 0.f), fmaxf(fmaf(acc[3], di, ba.w), 0.f));
        o.z = pack2bf(fmaxf(fmaf(acc[4], di, bb.x), 0.f), fmaxf(fmaf(acc[5], di, bb.y), 0.f));
        o.w = pack2bf(fmaxf(fmaf(acc[6], di, bb.z), 0.f), fmaxf(fmaf(acc[7], di, bb.w), 0.f));
        *(uint4*)&Albs[(tid >> 4) * 136 + lane * 8] = o;   // h1 row straight to A-tile
    }
    __syncthreads();

    // ---- phase B: 16-row MFMA gemm, 4 waves x 2 n-tiles ----
    int wv = tid >> 6;
    int lane = tid & 63;
    int c16 = lane & 15;
    int q = lane >> 4;

    floatx4 acc[2];
    acc[0] = (floatx4){0.f, 0.f, 0.f, 0.f};
    acc[1] = (floatx4){0.f, 0.f, 0.f, 0.f};

    const short8* WH = (const short8*)w2h;
    const short8* WL = (const short8*)w2l;
#pragma unroll
    for (int s = 0; s < 4; ++s) {
        short8 a = *(const short8*)&Albs[c16 * 136 + s * 32 + q * 8];
        int wb = s * 512 + c16 * 4 + q;
#pragma unroll
        for (int i = 0; i < 2; ++i) {
            int nt = wv * 2 + i;
            acc[i] = __builtin_amdgcn_mfma_f32_16x16x32_bf16(a, WH[wb + nt * 64], acc[i], 0, 0, 0);
            acc[i] = __builtin_amdgcn_mfma_f32_16x16x32_bf16(a, WL[wb + nt * 64], acc[i], 0, 0, 0);
        }
    }

    int rbase = row0 + q * 4;
#pragma unroll
    for (int r = 0; r < 4; ++r) {
        int row = rbase + r;
        float dv = dinv[row];
#pragma unroll
        for (int i = 0; i < 2; ++i) {
            int nt = wv * 2 + i;
            tmp2[row * 128 + nt * 16 + c16] = f2bf(acc[i][r] * dv);
        }
    }
}

// ---------------- layer-2 aggregation (standalone) ----------------
__global__ __launch_bounds__(256) void k_agg(const unsigned short* __restrict__ tmp16,
                                             const int* __restrict__ csr,
                                             const int* __restrict__ rowstart,
                                             const float* __restrict__ dinv,
                                             const float* __restrict__ bias,
                                             unsigned short* __restrict__ out16) {
    int node = (blockIdx.x * blockDim.x + threadIdx.x) >> 4;
    int lane = threadIdx.x & 15;
    if (node >= N) return;
    const uint4* t8 = (const uint4*)tmp16;
    float acc[8] = {0.f, 0.f, 0.f, 0.f, 0.f, 0.f, 0.f, 0.f};
    fma8(t8[node * 16 + lane], 1.0f, acc);
    agg_loop(t8, csr, rowstart[node], rowstart[node + 1], lane, acc);

    float di = dinv[node];
    const float4* b4 = (const float4*)bias;
    float4 ba = b4[lane * 2], bb = b4[lane * 2 + 1];
    uint4 o;
    o.x = pack2bf(fmaxf(fmaf(acc[0], di, ba.x), 0.f), fmaxf(fmaf(acc[1], di, ba.y), 0.f));
    o.y = pack2bf(fmaxf(fmaf(acc[2], di, ba.z), 0.f), fmaxf(fmaf(acc[3], di, ba.w), 0.f));
    o.z = pack2bf(fmaxf(fmaf(acc[4], di, bb.x), 0.f), fmaxf(fmaf(acc[5], di, bb.y), 0.f));
    o.w = pack2bf(fmaxf(fmaf(acc[6], di, bb.z), 0.f), fmaxf(fmaf(acc[7], di, bb.w), 0.f));
    ((uint4*)out16)[node * 16 + lane] = o;
}

// ---------------- mean-pool accumulate over bf16 h (batch is sorted) ----------------
__global__ void k_pool(const unsigned short* __restrict__ h16, const int* __restrict__ batch,
                       float* __restrict__ sums) {
    int grp = (blockIdx.x * blockDim.x + threadIdx.x) >> 4;
    int lane = threadIdx.x & 15;
    int base = grp * 64;
    if (base >= N) return;
    int end = (base + 64 < N) ? base + 64 : N;
    float acc[8] = {0.f, 0.f, 0.f, 0.f, 0.f, 0.f, 0.f, 0.f};
    const uint4* h4 = (const uint4*)h16;
    int curb = batch[base];
    for (int i = base; i < end; ++i) {
        int b = batch[i];
        if (b != curb) {
            float* sp = &sums[curb * F + lane * 8];
#pragma unroll
            for (int k = 0; k < 8; ++k) { atomicAdd(sp + k, acc[k]); acc[k] = 0.f; }
            curb = b;
        }
        fma8(h4[i * 16 + lane], 1.0f, acc);
    }
    float* sp = &sums[curb * F + lane * 8];
#pragma unroll
    for (int k = 0; k < 8; ++k) atomicAdd(sp + k, acc[k]);
}

// ---------------- fused fc + head: z = relu(pooled@Wfc+bfc); out = z@Wh + bh ----------------
__global__ __launch_bounds__(128) void k_fchead(const float* __restrict__ sums,
                                                const float* __restrict__ cnt,
                                                const float* __restrict__ Wfc,
                                                const float* __restrict__ bfc,
                                                const float* __restrict__ Wh,
                                                const float* __restrict__ bh,
                                                float* __restrict__ out) {
    __shared__ float p[128];
    __shared__ float zs[128];
    int g = blockIdx.x, t = threadIdx.x;
    float inv = 1.0f / fmaxf(cnt[g], 1.0f);
    p[t] = sums[g * F + t] * inv;
    __syncthreads();
    float acc = bfc[t];
    for (int k = 0; k < F; ++k) acc = fmaf(p[k], Wfc[k * F + t], acc);
    zs[t] = fmaxf(acc, 0.f);
    __syncthreads();
    if (t < T * 2) {
        int task = t >> 1, c = t & 1;
        float a = bh[task * 2 + c];
        const float* wr = &Wh[task * F * 2 + c];
        for (int h = 0; h < F; ++h) a = fmaf(zs[h], wr[h * 2], a);
        out[task * (G * 2) + g * 2 + c] = a;
    }
}

extern "C" void kernel_launch(void* const* d_in, const int* in_sizes, int n_in,
                              void* d_out, int out_size, void* d_ws, size_t ws_size,
                              hipStream_t stream) {
    const float* x    = (const float*)d_in[0];
    const int*   ei   = (const int*)d_in[1];      // [2,E]: row0=src, row1=dst
    const int*   batch= (const int*)d_in[2];
    const float* W1   = (const float*)d_in[3];
    const float* b1   = (const float*)d_in[4];
    const float* W2   = (const float*)d_in[5];
    const float* b2   = (const float*)d_in[6];
    const float* Wfc  = (const float*)d_in[7];
    const float* bfc  = (const float*)d_in[8];
    const float* Wh   = (const float*)d_in[9];
    const float* bh   = (const float*)d_in[10];
    float* out = (float*)d_out;

    const int* srcp = ei;
    const int* dstp = ei + E;

    char* w = (char*)d_ws;
    auto alloc = [&](size_t bytes) {
        char* p = w;
        w += (bytes + 255) & ~(size_t)255;
        return p;
    };
    unsigned short* tmp16 = (unsigned short*)alloc((size_t)N * F * 2);
    unsigned short* tmp2  = (unsigned short*)alloc((size_t)N * F * 2);
    unsigned short* hbuf16= (unsigned short*)alloc((size_t)N * F * 2);
    int*   csr      = (int*)  alloc((size_t)E * 4);
    int*   rowstart = (int*)  alloc((size_t)(N + 1) * 4);
    int*   fillpos8 = (int*)  alloc((size_t)8 * N * 4);
    int*   deg8     = (int*)  alloc((size_t)8 * N * 4);
    int*   deg      = (int*)  alloc((size_t)N * 4);
    float* dinv     = (float*)alloc((size_t)N * 4);
    int*   part     = (int*)  alloc((size_t)NBLK * 4);
    float* sums     = (float*)alloc((size_t)G * F * 4);
    float* cnt      = (float*)alloc((size_t)G * 4);
    unsigned short* w1h = (unsigned short*)alloc((size_t)F * F * 2);
    unsigned short* w1l = (unsigned short*)alloc((size_t)F * F * 2);
    unsigned short* w2h = (unsigned short*)alloc((size_t)F * F * 2);
    unsigned short* w2l = (unsigned short*)alloc((size_t)F * F * 2);

    hipMemsetAsync(deg8, 0, (size_t)8 * N * 4, stream);

    // fused preamble: wcast W1/W2, cntbs, 8-way deg histogram, zero sums
    k_pre<<<PRE_BLKS, 256, 0, stream>>>(W1, W2, w1h, w1l, w2h, w2l,
                                        dstp, deg8, batch, cnt, sums);

    // CSR build (two-level parallel scan; class-split fillpos8)
    k_part<<<NBLK, SCAN_B, 0, stream>>>(deg8, deg, part, dinv);
    k_scanpart<<<1, SCAN_B, 0, stream>>>(part);
    k_rowfill<<<NBLK, SCAN_B, 0, stream>>>(deg, deg8, part, rowstart, fillpos8);

    // fused: layer-1 GEMM (dinv-prescaled output) + plain-store CSR fill
    k_fillgemm<<<GB1 + DEG_BLKS, 256, 0, stream>>>(x, w1h, w1l, dinv, tmp16,
                                                   srcp, dstp, fillpos8, csr);

    // fused: layer-1 aggregation + layer-2 GEMM (h1 stays in LDS)
    k_agg1gemm<<<AGB, 256, 0, stream>>>(tmp16, csr, rowstart, dinv, b1, w2h, w2l, tmp2);

    // layer-2 aggregation
    k_agg<<<(N * 16 + 255) / 256, 256, 0, stream>>>(tmp2, csr, rowstart, dinv, b2, hbuf16);

    // pooling
    int ngrp = (N + 63) / 64;
    k_pool<<<(ngrp * 16 + 255) / 256, 256, 0, stream>>>(hbuf16, batch, sums);

    // fc + heads (fused)
    k_fchead<<<G, 128, 0, stream>>>(sums, cnt, Wfc, bfc, Wh, bh, out);
}

// Round 12
// 274.461 us; speedup vs baseline: 1.1380x; 1.0370x over previous
//
#include <hip/hip_runtime.h>
#include <math.h>

constexpr int N = 50000;   // nodes
constexpr int E = 800000;  // edges (without self-loops)
constexpr int F = 128;     // features / hidden
constexpr int G = 256;     // graphs
constexpr int T = 4;       // tasks

constexpr int BSH   = 5;                         // 32 nodes per bucket
constexpr int BNODES= 1 << BSH;
constexpr int NBUCK = (N + BNODES - 1) / BNODES; // 1563
constexpr int NCLS  = 8;                         // classes == XCDs
constexpr int CAP   = 128;                       // per (class,bucket) capacity; mean 64, 8-sigma safe

// k_pre block-range layout
constexpr int WC_BLKS  = (F * F + 255) / 256;    // 64
constexpr int DEG_BLKS = (E + 255) / 256;        // 3125 (pass-A chunks)
constexpr int SUM_BLKS = (G * F + 255) / 256;    // 128
constexpr int PRE_A0   = 2 * WC_BLKS + 1;        // 129
constexpr int PRE_SUM0 = PRE_A0 + DEG_BLKS;      // 3254
constexpr int PRE_BLKS = PRE_SUM0 + SUM_BLKS;    // 3382

constexpr int GB1 = (N + 63) / 64;               // 782 gemm blocks
constexpr int AGB = N / 16;                      // 3125 fused agg+gemm blocks

typedef __attribute__((ext_vector_type(8))) short short8;
typedef __attribute__((ext_vector_type(4))) float floatx4;

// bf16 <-> fp32 helpers (RNE on pack; values are finite)
__device__ inline float bf2f(unsigned short u) {
    union { unsigned int i; float f; } v;
    v.i = ((unsigned int)u) << 16;
    return v.f;
}
__device__ inline unsigned short f2bf(float f) {
    union { float f; unsigned int i; } v;
    v.f = f;
    unsigned int r = v.i + 0x7FFF + ((v.i >> 16) & 1);
    return (unsigned short)(r >> 16);
}
__device__ inline unsigned int pack2bf(float a, float b) {
    return (unsigned int)f2bf(a) | ((unsigned int)f2bf(b) << 16);
}

// pack W (fp32) -> MFMA-B-fragment order, hi/lo bf16 split
__device__ inline void wcast_one(const float* __restrict__ W,
                                 unsigned short* __restrict__ Whi,
                                 unsigned short* __restrict__ Wlo, int i) {
    if (i >= F * F) return;
    int k = i >> 7, n = i & 127;
    float w = W[i];
    unsigned short hi = f2bf(w);
    unsigned short lo = f2bf(w - bf2f(hi));
    int s = k >> 5, q = (k >> 3) & 3, j = k & 7;
    int idx = (((s * 128 + n) * 4 + q) * 8) + j;
    Whi[idx] = hi;
    Wlo[idx] = lo;
}

// ---------------- fused preamble: wcast(W1/W2), cntbs, PASS-A bucket scatter, zero(sums) ----
// Pass A: edges scattered into (class,bucket) staging segments; class = blockIdx&7
// == XCD, so each segment's frontier cache line is written by ONE XCD only ->
// write combining works, no cross-XCD line ping-pong.
__global__ __launch_bounds__(256) void k_pre(const float* __restrict__ W1, const float* __restrict__ W2,
                                             unsigned short* __restrict__ w1h, unsigned short* __restrict__ w1l,
                                             unsigned short* __restrict__ w2h, unsigned short* __restrict__ w2l,
                                             const int* __restrict__ src, const int* __restrict__ dst,
                                             int* __restrict__ bcnt, int2* __restrict__ staging,
                                             const int* __restrict__ batch, float* __restrict__ cnt,
                                             float* __restrict__ sums) {
    int b = blockIdx.x, t = threadIdx.x;
    if (b < WC_BLKS) {
        wcast_one(W1, w1h, w1l, b * 256 + t);
    } else if (b < 2 * WC_BLKS) {
        wcast_one(W2, w2h, w2l, (b - WC_BLKS) * 256 + t);
    } else if (b == 2 * WC_BLKS) {
        int g = t;
        int lo0 = 0, hi0 = N;
        while (lo0 < hi0) { int m = (lo0 + hi0) >> 1; if (batch[m] < g) lo0 = m + 1; else hi0 = m; }
        int lo1 = lo0, hi1 = N;
        while (lo1 < hi1) { int m = (lo1 + hi1) >> 1; if (batch[m] < g + 1) lo1 = m + 1; else hi1 = m; }
        cnt[g] = (float)(lo1 - lo0);
    } else if (b < PRE_SUM0) {
        int chunk = b - PRE_A0;
        int cls = b & 7;                      // XCD-pinned class
        int e = chunk * 256 + t;
        if (e < E) {
            int d = dst[e], s = src[e];
            int seg = cls * NBUCK + (d >> BSH);
            int pos = atomicAdd(&bcnt[seg], 1);
            if (pos < CAP) staging[seg * CAP + pos] = make_int2(s, d);
        }
    } else {
        int i = (b - PRE_SUM0) * 256 + t;
        if (i < G * F) sums[i] = 0.f;
    }
}

// ---------------- scan bucket totals -> bucketbase (exclusive) ----------------
__global__ __launch_bounds__(256) void k_bucketscan(const int* __restrict__ bcnt,
                                                    int* __restrict__ bucketbase) {
    __shared__ int part[256];
    int t = threadIdx.x;
    constexpr int CH = (NBUCK + 255) / 256;   // 7
    int beg = t * CH;
    int end = (beg + CH < NBUCK) ? beg + CH : NBUCK;
    int tot[CH];
    int s = 0;
    for (int i = beg; i < end; ++i) {
        int v = 0;
#pragma unroll
        for (int c = 0; c < NCLS; ++c) v += bcnt[c * NBUCK + i];
        tot[i - beg] = v;
        s += v;
    }
    part[t] = s;
    __syncthreads();
    for (int off = 1; off < 256; off <<= 1) {
        int u = (t >= off) ? part[t - off] : 0;
        __syncthreads();
        part[t] += u;
        __syncthreads();
    }
    int run = (t == 0) ? 0 : part[t - 1];
    for (int i = beg; i < end; ++i) {
        bucketbase[i] = run;
        run += tot[i - beg];
    }
    if (t == 255) bucketbase[NBUCK] = part[255];  // == E
}

// ---------------- pass B: per-bucket LDS counting sort -> csr, rowstart, dinv ----------------
// One block per bucket (32 nodes, ~512 edges). All csr writes land in the
// bucket's contiguous ~2KB range from a single block -> zero write amp.
__global__ __launch_bounds__(256) void k_passB(const int* __restrict__ bcnt,
                                               const int2* __restrict__ staging,
                                               const int* __restrict__ bucketbase,
                                               int* __restrict__ csr,
                                               int* __restrict__ rowstart,
                                               float* __restrict__ dinv) {
    __shared__ int so[NCLS + 1];
    __shared__ int2 ent[NCLS * CAP];          // 8 KB
    __shared__ int h[BNODES], off[BNODES], off_a[BNODES];
    int b = blockIdx.x, t = threadIdx.x;

    if (t == 0) {
        int run = 0;
        for (int c = 0; c < NCLS; ++c) {
            so[c] = run;
            int v = bcnt[c * NBUCK + b];
            run += (v < CAP) ? v : CAP;
        }
        so[NCLS] = run;
    }
    if (t < BNODES) h[t] = 0;
    __syncthreads();
    int M = so[NCLS];

    // load staged entries + LDS histogram of dst
    for (int i = t; i < M; i += 256) {
        int c = 0;
        while (i >= so[c + 1]) ++c;
        int2 en = staging[(c * NBUCK + b) * CAP + (i - so[c])];
        ent[i] = en;
        atomicAdd(&h[en.y & (BNODES - 1)], 1);
    }
    __syncthreads();

    // node offsets (serial over 32 — trivial), rowstart, dinv
    if (t == 0) {
        int run = bucketbase[b];
        for (int k = 0; k < BNODES; ++k) {
            off[k] = run;
            off_a[k] = run;
            run += h[k];
        }
    }
    __syncthreads();
    if (t < BNODES) {
        int node = b * BNODES + t;
        if (node < N) {
            rowstart[node] = off[t];
            dinv[node] = rsqrtf((float)(h[t] + 1));   // +1 self-loop
        }
    }
    if (b == 0 && t == 0) rowstart[N] = E;

    // scatter into contiguous csr range
    for (int i = t; i < M; i += 256) {
        int loc = atomicAdd(&off_a[ent[i].y & (BNODES - 1)], 1);
        csr[loc] = ent[i].x;
    }
}

// ---------------- MFMA GEMM body (64-row tile): C16 = dinv[row] * (A @ W) ----------------
template <bool ABF16>
__device__ __forceinline__ void gemm_body(const void* __restrict__ Ain,
                                          const unsigned short* __restrict__ Wph,
                                          const unsigned short* __restrict__ Wpl,
                                          const float* __restrict__ dinv,
                                          unsigned short* __restrict__ C16,
                                          int row0, int tid) {
    __shared__ __align__(16) unsigned short Albs[64 * 136];  // row-major, pad 136

    if (ABF16) {
        const uint4* A8 = (const uint4*)Ain;
        for (int f = tid; f < 64 * 16; f += 256) {
            int r = f >> 4, kq = f & 15;
            int row = row0 + r;
            uint4 v = make_uint4(0u, 0u, 0u, 0u);
            if (row < N) v = A8[row * 16 + kq];
            *(uint4*)&Albs[r * 136 + kq * 8] = v;
        }
    } else {
        const float4* A4 = (const float4*)Ain;
        for (int f = tid; f < 64 * 32; f += 256) {
            int r = f >> 5, kq = f & 31;
            int row = row0 + r;
            float4 v = make_float4(0.f, 0.f, 0.f, 0.f);
            if (row < N) v = A4[row * 32 + kq];
            ushort4 o;
            o.x = f2bf(v.x); o.y = f2bf(v.y); o.z = f2bf(v.z); o.w = f2bf(v.w);
            *(ushort4*)&Albs[r * 136 + kq * 4] = o;
        }
    }
    __syncthreads();

    int wv = tid >> 6;
    int lane = tid & 63;
    int c16 = lane & 15;
    int q = lane >> 4;
    int m = wv * 16 + c16;

    floatx4 acc[8];
#pragma unroll
    for (int nt = 0; nt < 8; ++nt) acc[nt] = (floatx4){0.f, 0.f, 0.f, 0.f};

    const short8* WH = (const short8*)Wph;
    const short8* WL = (const short8*)Wpl;
#pragma unroll
    for (int s = 0; s < 4; ++s) {
        short8 a = *(const short8*)&Albs[m * 136 + s * 32 + q * 8];
        int wb = s * 512 + c16 * 4 + q;
#pragma unroll
        for (int nt = 0; nt < 8; ++nt) {
            acc[nt] = __builtin_amdgcn_mfma_f32_16x16x32_bf16(a, WH[wb + nt * 64], acc[nt], 0, 0, 0);
            acc[nt] = __builtin_amdgcn_mfma_f32_16x16x32_bf16(a, WL[wb + nt * 64], acc[nt], 0, 0, 0);
        }
    }

    int rbase = row0 + wv * 16 + q * 4;
#pragma unroll
    for (int r = 0; r < 4; ++r) {
        int row = rbase + r;
        if (row < N) {
            float dv = dinv[row];
#pragma unroll
            for (int nt = 0; nt < 8; ++nt)
                C16[row * 128 + nt * 16 + c16] = f2bf(acc[nt][r] * dv);
        }
    }
}

template <bool ABF16>
__global__ __launch_bounds__(256) void k_gemm(const void* __restrict__ Ain,
                                              const unsigned short* __restrict__ Wph,
                                              const unsigned short* __restrict__ Wpl,
                                              const float* __restrict__ dinv,
                                              unsigned short* __restrict__ C16) {
    gemm_body<ABF16>(Ain, Wph, Wpl, dinv, C16, blockIdx.x * 64, threadIdx.x);
}

// 8 bf16 (uint4) fma into 8 fp32 accumulators
__device__ inline void fma8(const uint4& u, float c, float* acc) {
    union { unsigned int i; float f; } a;
    a.i = u.x << 16;          acc[0] = fmaf(a.f, c, acc[0]);
    a.i = u.x & 0xFFFF0000u;  acc[1] = fmaf(a.f, c, acc[1]);
    a.i = u.y << 16;          acc[2] = fmaf(a.f, c, acc[2]);
    a.i = u.y & 0xFFFF0000u;  acc[3] = fmaf(a.f, c, acc[3]);
    a.i = u.z << 16;          acc[4] = fmaf(a.f, c, acc[4]);
    a.i = u.z & 0xFFFF0000u;  acc[5] = fmaf(a.f, c, acc[5]);
    a.i = u.w << 16;          acc[6] = fmaf(a.f, c, acc[6]);
    a.i = u.w & 0xFFFF0000u;  acc[7] = fmaf(a.f, c, acc[7]);
}

// agg inner loop: acc += Sum_{j in [jb,je)} tmp[csr[j]] (8-deep in flight)
__device__ __forceinline__ void agg_loop(const uint4* __restrict__ t8,
                                         const int* __restrict__ csr,
                                         int jb, int je, int lane, float* acc) {
    for (int j = jb; j < je; j += 8) {
        int e[8];
        float msk[8];
#pragma unroll
        for (int k = 0; k < 8; ++k) {
            int idx = j + k;
            e[k] = csr[idx < je ? idx : je - 1];
            msk[k] = (idx < je) ? 1.0f : 0.0f;
        }
        uint4 u[8];
#pragma unroll
        for (int k = 0; k < 8; ++k) u[k] = t8[e[k] * 16 + lane];
#pragma unroll
        for (int k = 0; k < 8; ++k) fma8(u[k], msk[k], acc);
    }
}

// ---------------- fused layer-1 agg + layer-2 GEMM (16 nodes/block) ----------------
__global__ __launch_bounds__(256) void k_agg1gemm(const unsigned short* __restrict__ tmp16,
                                                  const int* __restrict__ csr,
                                                  const int* __restrict__ rowstart,
                                                  const float* __restrict__ dinv,
                                                  const float* __restrict__ bias,
                                                  const unsigned short* __restrict__ w2h,
                                                  const unsigned short* __restrict__ w2l,
                                                  unsigned short* __restrict__ tmp2) {
    __shared__ __align__(16) unsigned short Albs[16 * 136];
    int tid = threadIdx.x;
    int row0 = blockIdx.x * 16;

    // ---- phase A: aggregation ----
    {
        int node = row0 + (tid >> 4);
        int lane = tid & 15;
        const uint4* t8 = (const uint4*)tmp16;
        float acc[8] = {0.f, 0.f, 0.f, 0.f, 0.f, 0.f, 0.f, 0.f};
        fma8(t8[node * 16 + lane], 1.0f, acc);
        agg_loop(t8, csr, rowstart[node], rowstart[node + 1], lane, acc);

        float di = dinv[node];
        const float4* b4 = (const float4*)bias;
        float4 ba = b4[lane * 2], bb = b4[lane * 2 + 1];
        uint4 o;
        o.x = pack2bf(fmaxf(fmaf(acc[0], di, ba.x), 0.f), fmaxf(fmaf(acc[1], di, ba.y), 0.f));
        o.y = pack2bf(fmaxf(fmaf(acc[2], di, ba.z), 0.f), fmaxf(fmaf(acc[3], di, ba.w), 0.f));
        o.z = pack2bf(fmaxf(fmaf(acc[4], di, bb.x), 0.f), fmaxf(fmaf(acc[5], di, bb.y), 0.f));
        o.w = pack2bf(fmaxf(fmaf(acc[6], di, bb.z), 0.f), fmaxf(fmaf(acc[7], di, bb.w), 0.f));
        *(uint4*)&Albs[(tid >> 4) * 136 + lane * 8] = o;
    }
    __syncthreads();

    // ---- phase B: 16-row MFMA gemm, 4 waves x 2 n-tiles ----
    int wv = tid >> 6;
    int lane = tid & 63;
    int c16 = lane & 15;
    int q = lane >> 4;

    floatx4 acc[2];
    acc[0] = (floatx4){0.f, 0.f, 0.f, 0.f};
    acc[1] = (floatx4){0.f, 0.f, 0.f, 0.f};

    const short8* WH = (const short8*)w2h;
    const short8* WL = (const short8*)w2l;
#pragma unroll
    for (int s = 0; s < 4; ++s) {
        short8 a = *(const short8*)&Albs[c16 * 136 + s * 32 + q * 8];
        int wb = s * 512 + c16 * 4 + q;
#pragma unroll
        for (int i = 0; i < 2; ++i) {
            int nt = wv * 2 + i;
            acc[i] = __builtin_amdgcn_mfma_f32_16x16x32_bf16(a, WH[wb + nt * 64], acc[i], 0, 0, 0);
            acc[i] = __builtin_amdgcn_mfma_f32_16x16x32_bf16(a, WL[wb + nt * 64], acc[i], 0, 0, 0);
        }
    }

    int rbase = row0 + q * 4;
#pragma unroll
    for (int r = 0; r < 4; ++r) {
        int row = rbase + r;
        float dv = dinv[row];
#pragma unroll
        for (int i = 0; i < 2; ++i) {
            int nt = wv * 2 + i;
            tmp2[row * 128 + nt * 16 + c16] = f2bf(acc[i][r] * dv);
        }
    }
}

// ---------------- layer-2 aggregation (standalone) ----------------
__global__ __launch_bounds__(256) void k_agg(const unsigned short* __restrict__ tmp16,
                                             const int* __restrict__ csr,
                                             const int* __restrict__ rowstart,
                                             const float* __restrict__ dinv,
                                             const float* __restrict__ bias,
                                             unsigned short* __restrict__ out16) {
    int node = (blockIdx.x * blockDim.x + threadIdx.x) >> 4;
    int lane = threadIdx.x & 15;
    if (node >= N) return;
    const uint4* t8 = (const uint4*)tmp16;
    float acc[8] = {0.f, 0.f, 0.f, 0.f, 0.f, 0.f, 0.f, 0.f};
    fma8(t8[node * 16 + lane], 1.0f, acc);
    agg_loop(t8, csr, rowstart[node], rowstart[node + 1], lane, acc);

    float di = dinv[node];
    const float4* b4 = (const float4*)bias;
    float4 ba = b4[lane * 2], bb = b4[lane * 2 + 1];
    uint4 o;
    o.x = pack2bf(fmaxf(fmaf(acc[0], di, ba.x), 0.f), fmaxf(fmaf(acc[1], di, ba.y), 0.f));
    o.y = pack2bf(fmaxf(fmaf(acc[2], di, ba.z), 0.f), fmaxf(fmaf(acc[3], di, ba.w), 0.f));
    o.z = pack2bf(fmaxf(fmaf(acc[4], di, bb.x), 0.f), fmaxf(fmaf(acc[5], di, bb.y), 0.f));
    o.w = pack2bf(fmaxf(fmaf(acc[6], di, bb.z), 0.f), fmaxf(fmaf(acc[7], di, bb.w), 0.f));
    ((uint4*)out16)[node * 16 + lane] = o;
}

// ---------------- mean-pool accumulate over bf16 h (batch is sorted) ----------------
__global__ void k_pool(const unsigned short* __restrict__ h16, const int* __restrict__ batch,
                       float* __restrict__ sums) {
    int grp = (blockIdx.x * blockDim.x + threadIdx.x) >> 4;
    int lane = threadIdx.x & 15;
    int base = grp * 64;
    if (base >= N) return;
    int end = (base + 64 < N) ? base + 64 : N;
    float acc[8] = {0.f, 0.f, 0.f, 0.f, 0.f, 0.f, 0.f, 0.f};
    const uint4* h4 = (const uint4*)h16;
    int curb = batch[base];
    for (int i = base; i < end; ++i) {
        int b = batch[i];
        if (b != curb) {
            float* sp = &sums[curb * F + lane * 8];
#pragma unroll
            for (int k = 0; k < 8; ++k) { atomicAdd(sp + k, acc[k]); acc[k] = 0.f; }
            curb = b;
        }
        fma8(h4[i * 16 + lane], 1.0f, acc);
    }
    float* sp = &sums[curb * F + lane * 8];
#pragma unroll
    for (int k = 0; k < 8; ++k) atomicAdd(sp + k, acc[k]);
}

// ---------------- fused fc + head ----------------
__global__ __launch_bounds__(128) void k_fchead(const float* __restrict__ sums,
                                                const float* __restrict__ cnt,
                                                const float* __restrict__ Wfc,
                                                const float* __restrict__ bfc,
                                                const float* __restrict__ Wh,
                                                const float* __restrict__ bh,
                                                float* __restrict__ out) {
    __shared__ float p[128];
    __shared__ float zs[128];
    int g = blockIdx.x, t = threadIdx.x;
    float inv = 1.0f / fmaxf(cnt[g], 1.0f);
    p[t] = sums[g * F + t] * inv;
    __syncthreads();
    float acc = bfc[t];
    for (int k = 0; k < F; ++k) acc = fmaf(p[k], Wfc[k * F + t], acc);
    zs[t] = fmaxf(acc, 0.f);
    __syncthreads();
    if (t < T * 2) {
        int task = t >> 1, c = t & 1;
        float a = bh[task * 2 + c];
        const float* wr = &Wh[task * F * 2 + c];
        for (int h = 0; h < F; ++h) a = fmaf(zs[h], wr[h * 2], a);
        out[task * (G * 2) + g * 2 + c] = a;
    }
}

extern "C" void kernel_launch(void* const* d_in, const int* in_sizes, int n_in,
                              void* d_out, int out_size, void* d_ws, size_t ws_size,
                              hipStream_t stream) {
    const float* x    = (const float*)d_in[0];
    const int*   ei   = (const int*)d_in[1];      // [2,E]: row0=src, row1=dst
    const int*   batch= (const int*)d_in[2];
    const float* W1   = (const float*)d_in[3];
    const float* b1   = (const float*)d_in[4];
    const float* W2   = (const float*)d_in[5];
    const float* b2   = (const float*)d_in[6];
    const float* Wfc  = (const float*)d_in[7];
    const float* bfc  = (const float*)d_in[8];
    const float* Wh   = (const float*)d_in[9];
    const float* bh   = (const float*)d_in[10];
    float* out = (float*)d_out;

    const int* srcp = ei;
    const int* dstp = ei + E;

    char* w = (char*)d_ws;
    auto alloc = [&](size_t bytes) {
        char* p = w;
        w += (bytes + 255) & ~(size_t)255;
        return p;
    };
    unsigned short* tmp16 = (unsigned short*)alloc((size_t)N * F * 2);
    unsigned short* tmp2  = (unsigned short*)alloc((size_t)N * F * 2);
    unsigned short* hbuf16= (unsigned short*)alloc((size_t)N * F * 2);
    int*   csr      = (int*)  alloc((size_t)E * 4);
    int2*  staging  = (int2*) alloc((size_t)NCLS * NBUCK * CAP * 8);
    int*   bcnt     = (int*)  alloc((size_t)NCLS * NBUCK * 4);
    int*   bucketbase=(int*)  alloc((size_t)(NBUCK + 1) * 4);
    int*   rowstart = (int*)  alloc((size_t)(N + 1) * 4);
    float* dinv     = (float*)alloc((size_t)N * 4);
    float* sums     = (float*)alloc((size_t)G * F * 4);
    float* cnt      = (float*)alloc((size_t)G * 4);
    unsigned short* w1h = (unsigned short*)alloc((size_t)F * F * 2);
    unsigned short* w1l = (unsigned short*)alloc((size_t)F * F * 2);
    unsigned short* w2h = (unsigned short*)alloc((size_t)F * F * 2);
    unsigned short* w2l = (unsigned short*)alloc((size_t)F * F * 2);

    hipMemsetAsync(bcnt, 0, (size_t)NCLS * NBUCK * 4, stream);

    // fused preamble: wcast W1/W2, cntbs, pass-A bucket scatter, zero sums
    k_pre<<<PRE_BLKS, 256, 0, stream>>>(W1, W2, w1h, w1l, w2h, w2l,
                                        srcp, dstp, bcnt, staging, batch, cnt, sums);

    // bucket totals -> bases; per-bucket counting sort -> csr/rowstart/dinv
    k_bucketscan<<<1, 256, 0, stream>>>(bcnt, bucketbase);
    k_passB<<<NBUCK, 256, 0, stream>>>(bcnt, staging, bucketbase, csr, rowstart, dinv);

    // layer-1 GEMM (dinv-prescaled output)
    k_gemm<false><<<GB1, 256, 0, stream>>>(x, w1h, w1l, dinv, tmp16);

    // fused: layer-1 aggregation + layer-2 GEMM (h1 stays in LDS)
    k_agg1gemm<<<AGB, 256, 0, stream>>>(tmp16, csr, rowstart, dinv, b1, w2h, w2l, tmp2);

    // layer-2 aggregation
    k_agg<<<(N * 16 + 255) / 256, 256, 0, stream>>>(tmp2, csr, rowstart, dinv, b2, hbuf16);

    // pooling
    int ngrp = (N + 63) / 64;
    k_pool<<<(ngrp * 16 + 255) / 256, 256, 0, stream>>>(hbuf16, batch, sums);

    // fc + heads (fused)
    k_fchead<<<G, 128, 0, stream>>>(sums, cnt, Wfc, bfc, Wh, bh, out);
}

// Round 13
// 264.851 us; speedup vs baseline: 1.1793x; 1.0363x over previous
//
#include <hip/hip_runtime.h>
#include <math.h>

constexpr int N = 50000;   // nodes
constexpr int E = 800000;  // edges (without self-loops)
constexpr int F = 128;     // features / hidden
constexpr int G = 256;     // graphs
constexpr int T = 4;       // tasks

constexpr int BSH   = 5;                         // 32 nodes per bucket
constexpr int BNODES= 1 << BSH;
constexpr int NBUCK = (N + BNODES - 1) / BNODES; // 1563
constexpr int CHUNK = 8192;                      // edges per partition block
constexpr int NCHUNK= (E + CHUNK - 1) / CHUNK;   // 98

// k_pre block-range layout
constexpr int WC_BLKS  = (F * F + 255) / 256;    // 64
constexpr int SUM_BLKS = (G * F + 255) / 256;    // 128
constexpr int PRE_H0   = 2 * WC_BLKS + 1;        // 129 (hist chunks)
constexpr int PRE_SUM0 = PRE_H0 + NCHUNK;        // 227
constexpr int PRE_BLKS = PRE_SUM0 + SUM_BLKS;    // 355

constexpr int GB1 = (N + 63) / 64;               // 782 gemm blocks
constexpr int AGB = N / 16;                      // 3125 fused agg+gemm blocks

typedef __attribute__((ext_vector_type(8))) short short8;
typedef __attribute__((ext_vector_type(4))) float floatx4;

// bf16 <-> fp32 helpers (RNE on pack; values are finite)
__device__ inline float bf2f(unsigned short u) {
    union { unsigned int i; float f; } v;
    v.i = ((unsigned int)u) << 16;
    return v.f;
}
__device__ inline unsigned short f2bf(float f) {
    union { float f; unsigned int i; } v;
    v.f = f;
    unsigned int r = v.i + 0x7FFF + ((v.i >> 16) & 1);
    return (unsigned short)(r >> 16);
}
__device__ inline unsigned int pack2bf(float a, float b) {
    return (unsigned int)f2bf(a) | ((unsigned int)f2bf(b) << 16);
}

// pack W (fp32) -> MFMA-B-fragment order, hi/lo bf16 split
__device__ inline void wcast_one(const float* __restrict__ W,
                                 unsigned short* __restrict__ Whi,
                                 unsigned short* __restrict__ Wlo, int i) {
    if (i >= F * F) return;
    int k = i >> 7, n = i & 127;
    float w = W[i];
    unsigned short hi = f2bf(w);
    unsigned short lo = f2bf(w - bf2f(hi));
    int s = k >> 5, q = (k >> 3) & 3, j = k & 7;
    int idx = (((s * 128 + n) * 4 + q) * 8) + j;
    Whi[idx] = hi;
    Wlo[idx] = lo;
}

// ---------------- fused preamble: wcast(W1/W2), cntbs, LDS bucket-hist, zero(sums) ----------
// Histogram is per-chunk in LDS (no global atomics); counts dumped coalesced.
__global__ __launch_bounds__(256) void k_pre(const float* __restrict__ W1, const float* __restrict__ W2,
                                             unsigned short* __restrict__ w1h, unsigned short* __restrict__ w1l,
                                             unsigned short* __restrict__ w2h, unsigned short* __restrict__ w2l,
                                             const int* __restrict__ dst, int* __restrict__ cnts,
                                             const int* __restrict__ batch, float* __restrict__ cnt,
                                             float* __restrict__ sums) {
    __shared__ int h[NBUCK];
    int b = blockIdx.x, t = threadIdx.x;
    if (b < WC_BLKS) {
        wcast_one(W1, w1h, w1l, b * 256 + t);
    } else if (b < 2 * WC_BLKS) {
        wcast_one(W2, w2h, w2l, (b - WC_BLKS) * 256 + t);
    } else if (b == 2 * WC_BLKS) {
        int g = t;
        int lo0 = 0, hi0 = N;
        while (lo0 < hi0) { int m = (lo0 + hi0) >> 1; if (batch[m] < g) lo0 = m + 1; else hi0 = m; }
        int lo1 = lo0, hi1 = N;
        while (lo1 < hi1) { int m = (lo1 + hi1) >> 1; if (batch[m] < g + 1) lo1 = m + 1; else hi1 = m; }
        cnt[g] = (float)(lo1 - lo0);
    } else if (b < PRE_SUM0) {
        int chunk = b - PRE_H0;
        for (int i = t; i < NBUCK; i += 256) h[i] = 0;
        __syncthreads();
        int base = chunk * CHUNK;
        for (int i = t; i < CHUNK; i += 256) {
            int e = base + i;
            if (e < E) atomicAdd(&h[dst[e] >> BSH], 1);   // LDS atomic
        }
        __syncthreads();
        for (int i = t; i < NBUCK; i += 256) cnts[chunk * NBUCK + i] = h[i];
    } else {
        int i = (b - PRE_SUM0) * 256 + t;
        if (i < G * F) sums[i] = 0.f;
    }
}

// ---------------- per-bucket scan over chunks: cnts -> within-bucket offsets + totals --------
__global__ __launch_bounds__(256) void k_colscan(int* __restrict__ cnts, int* __restrict__ btot) {
    int j = blockIdx.x * 256 + threadIdx.x;
    if (j >= NBUCK) return;
    int run = 0;
    for (int k = 0; k < NCHUNK; ++k) {        // column access: coalesced across threads
        int v = cnts[k * NBUCK + j];
        cnts[k * NBUCK + j] = run;
        run += v;
    }
    btot[j] = run;
}

// ---------------- scan bucket totals -> bucketbase (exclusive) ----------------
__global__ __launch_bounds__(256) void k_bucketscan(const int* __restrict__ btot,
                                                    int* __restrict__ bucketbase) {
    __shared__ int part[256];
    int t = threadIdx.x;
    constexpr int CH = (NBUCK + 255) / 256;   // 7
    int beg = t * CH;
    int end = (beg + CH < NBUCK) ? beg + CH : NBUCK;
    int tot[CH];
    int s = 0;
    for (int i = beg; i < end; ++i) {
        tot[i - beg] = btot[i];
        s += btot[i];
    }
    part[t] = s;
    __syncthreads();
    for (int off = 1; off < 256; off <<= 1) {
        int u = (t >= off) ? part[t - off] : 0;
        __syncthreads();
        part[t] += u;
        __syncthreads();
    }
    int run = (t == 0) ? 0 : part[t - 1];
    for (int i = beg; i < end; ++i) {
        bucketbase[i] = run;
        run += tot[i - beg];
    }
    if (t == 255) bucketbase[NBUCK] = part[255];  // == E
}

// ---------------- deterministic partition: edges -> bucket-contiguous staging (4B packed) ----
// Position = bucketbase[b] + cnts[chunk][b] + LDS-running-count. Zero global atomics.
__global__ __launch_bounds__(256) void k_fillb(const int* __restrict__ src,
                                               const int* __restrict__ dst,
                                               const int* __restrict__ cnts,
                                               const int* __restrict__ bucketbase,
                                               unsigned int* __restrict__ staging) {
    __shared__ int lofs[NBUCK];
    int chunk = blockIdx.x, t = threadIdx.x;
    for (int i = t; i < NBUCK; i += 256)
        lofs[i] = bucketbase[i] + cnts[chunk * NBUCK + i];
    __syncthreads();
    int base = chunk * CHUNK;
    for (int i = t; i < CHUNK; i += 256) {
        int e = base + i;
        if (e < E) {
            int d = dst[e];
            int pos = atomicAdd(&lofs[d >> BSH], 1);      // LDS atomic
            staging[pos] = (unsigned int)src[e] | ((unsigned int)(d & (BNODES - 1)) << 16);
        }
    }
}

// ---------------- pass B: per-bucket LDS counting sort -> csr, rowstart, dinv ----------------
__global__ __launch_bounds__(256) void k_passB(const unsigned int* __restrict__ staging,
                                               const int* __restrict__ bucketbase,
                                               int* __restrict__ csr,
                                               int* __restrict__ rowstart,
                                               float* __restrict__ dinv) {
    __shared__ unsigned int ent[1024];        // mean 512, 11-sigma safe
    __shared__ int h[BNODES], off[BNODES], off_a[BNODES];
    int b = blockIdx.x, t = threadIdx.x;
    int jb = bucketbase[b], je = bucketbase[b + 1];
    int M = je - jb;
    if (M > 1024) M = 1024;
    if (t < BNODES) h[t] = 0;
    __syncthreads();

    for (int i = t; i < M; i += 256) {
        unsigned int en = staging[jb + i];
        ent[i] = en;
        atomicAdd(&h[(en >> 16) & (BNODES - 1)], 1);
    }
    __syncthreads();

    if (t == 0) {
        int run = jb;
        for (int k = 0; k < BNODES; ++k) {
            off[k] = run;
            off_a[k] = run;
            run += h[k];
        }
    }
    __syncthreads();
    if (t < BNODES) {
        int node = b * BNODES + t;
        if (node < N) {
            rowstart[node] = off[t];
            dinv[node] = rsqrtf((float)(h[t] + 1));   // +1 self-loop
        }
    }
    if (b == 0 && t == 0) rowstart[N] = E;

    for (int i = t; i < M; i += 256) {
        unsigned int en = ent[i];
        int loc = atomicAdd(&off_a[(en >> 16) & (BNODES - 1)], 1);
        csr[loc] = (int)(en & 0xFFFFu);
    }
}

// ---------------- MFMA GEMM body (64-row tile): C16 = dinv[row] * (A @ W) ----------------
template <bool ABF16>
__device__ __forceinline__ void gemm_body(const void* __restrict__ Ain,
                                          const unsigned short* __restrict__ Wph,
                                          const unsigned short* __restrict__ Wpl,
                                          const float* __restrict__ dinv,
                                          unsigned short* __restrict__ C16,
                                          int row0, int tid) {
    __shared__ __align__(16) unsigned short Albs[64 * 136];  // row-major, pad 136

    if (ABF16) {
        const uint4* A8 = (const uint4*)Ain;
        for (int f = tid; f < 64 * 16; f += 256) {
            int r = f >> 4, kq = f & 15;
            int row = row0 + r;
            uint4 v = make_uint4(0u, 0u, 0u, 0u);
            if (row < N) v = A8[row * 16 + kq];
            *(uint4*)&Albs[r * 136 + kq * 8] = v;
        }
    } else {
        const float4* A4 = (const float4*)Ain;
        for (int f = tid; f < 64 * 32; f += 256) {
            int r = f >> 5, kq = f & 31;
            int row = row0 + r;
            float4 v = make_float4(0.f, 0.f, 0.f, 0.f);
            if (row < N) v = A4[row * 32 + kq];
            ushort4 o;
            o.x = f2bf(v.x); o.y = f2bf(v.y); o.z = f2bf(v.z); o.w = f2bf(v.w);
            *(ushort4*)&Albs[r * 136 + kq * 4] = o;
        }
    }
    __syncthreads();

    int wv = tid >> 6;
    int lane = tid & 63;
    int c16 = lane & 15;
    int q = lane >> 4;
    int m = wv * 16 + c16;

    floatx4 acc[8];
#pragma unroll
    for (int nt = 0; nt < 8; ++nt) acc[nt] = (floatx4){0.f, 0.f, 0.f, 0.f};

    const short8* WH = (const short8*)Wph;
    const short8* WL = (const short8*)Wpl;
#pragma unroll
    for (int s = 0; s < 4; ++s) {
        short8 a = *(const short8*)&Albs[m * 136 + s * 32 + q * 8];
        int wb = s * 512 + c16 * 4 + q;
#pragma unroll
        for (int nt = 0; nt < 8; ++nt) {
            acc[nt] = __builtin_amdgcn_mfma_f32_16x16x32_bf16(a, WH[wb + nt * 64], acc[nt], 0, 0, 0);
            acc[nt] = __builtin_amdgcn_mfma_f32_16x16x32_bf16(a, WL[wb + nt * 64], acc[nt], 0, 0, 0);
        }
    }

    int rbase = row0 + wv * 16 + q * 4;
#pragma unroll
    for (int r = 0; r < 4; ++r) {
        int row = rbase + r;
        if (row < N) {
            float dv = dinv[row];
#pragma unroll
            for (int nt = 0; nt < 8; ++nt)
                C16[row * 128 + nt * 16 + c16] = f2bf(acc[nt][r] * dv);
        }
    }
}

template <bool ABF16>
__global__ __launch_bounds__(256) void k_gemm(const void* __restrict__ Ain,
                                              const unsigned short* __restrict__ Wph,
                                              const unsigned short* __restrict__ Wpl,
                                              const float* __restrict__ dinv,
                                              unsigned short* __restrict__ C16) {
    gemm_body<ABF16>(Ain, Wph, Wpl, dinv, C16, blockIdx.x * 64, threadIdx.x);
}

// 8 bf16 (uint4) fma into 8 fp32 accumulators
__device__ inline void fma8(const uint4& u, float c, float* acc) {
    union { unsigned int i; float f; } a;
    a.i = u.x << 16;          acc[0] = fmaf(a.f, c, acc[0]);
    a.i = u.x & 0xFFFF0000u;  acc[1] = fmaf(a.f, c, acc[1]);
    a.i = u.y << 16;          acc[2] = fmaf(a.f, c, acc[2]);
    a.i = u.y & 0xFFFF0000u;  acc[3] = fmaf(a.f, c, acc[3]);
    a.i = u.z << 16;          acc[4] = fmaf(a.f, c, acc[4]);
    a.i = u.z & 0xFFFF0000u;  acc[5] = fmaf(a.f, c, acc[5]);
    a.i = u.w << 16;          acc[6] = fmaf(a.f, c, acc[6]);
    a.i = u.w & 0xFFFF0000u;  acc[7] = fmaf(a.f, c, acc[7]);
}

// agg inner loop: acc += Sum_{j in [jb,je)} tmp[csr[j]] (8-deep in flight)
__device__ __forceinline__ void agg_loop(const uint4* __restrict__ t8,
                                         const int* __restrict__ csr,
                                         int jb, int je, int lane, float* acc) {
    for (int j = jb; j < je; j += 8) {
        int e[8];
        float msk[8];
#pragma unroll
        for (int k = 0; k < 8; ++k) {
            int idx = j + k;
            e[k] = csr[idx < je ? idx : je - 1];
            msk[k] = (idx < je) ? 1.0f : 0.0f;
        }
        uint4 u[8];
#pragma unroll
        for (int k = 0; k < 8; ++k) u[k] = t8[e[k] * 16 + lane];
#pragma unroll
        for (int k = 0; k < 8; ++k) fma8(u[k], msk[k], acc);
    }
}

// ---------------- fused layer-1 agg + layer-2 GEMM (16 nodes/block) ----------------
__global__ __launch_bounds__(256) void k_agg1gemm(const unsigned short* __restrict__ tmp16,
                                                  const int* __restrict__ csr,
                                                  const int* __restrict__ rowstart,
                                                  const float* __restrict__ dinv,
                                                  const float* __restrict__ bias,
                                                  const unsigned short* __restrict__ w2h,
                                                  const unsigned short* __restrict__ w2l,
                                                  unsigned short* __restrict__ tmp2) {
    __shared__ __align__(16) unsigned short Albs[16 * 136];
    int tid = threadIdx.x;
    int row0 = blockIdx.x * 16;

    // ---- phase A: aggregation ----
    {
        int node = row0 + (tid >> 4);
        int lane = tid & 15;
        const uint4* t8 = (const uint4*)tmp16;
        float acc[8] = {0.f, 0.f, 0.f, 0.f, 0.f, 0.f, 0.f, 0.f};
        fma8(t8[node * 16 + lane], 1.0f, acc);
        agg_loop(t8, csr, rowstart[node], rowstart[node + 1], lane, acc);

        float di = dinv[node];
        const float4* b4 = (const float4*)bias;
        float4 ba = b4[lane * 2], bb = b4[lane * 2 + 1];
        uint4 o;
        o.x = pack2bf(fmaxf(fmaf(acc[0], di, ba.x), 0.f), fmaxf(fmaf(acc[1], di, ba.y), 0.f));
        o.y = pack2bf(fmaxf(fmaf(acc[2], di, ba.z), 0.f), fmaxf(fmaf(acc[3], di, ba.w), 0.f));
        o.z = pack2bf(fmaxf(fmaf(acc[4], di, bb.x), 0.f), fmaxf(fmaf(acc[5], di, bb.y), 0.f));
        o.w = pack2bf(fmaxf(fmaf(acc[6], di, bb.z), 0.f), fmaxf(fmaf(acc[7], di, bb.w), 0.f));
        *(uint4*)&Albs[(tid >> 4) * 136 + lane * 8] = o;
    }
    __syncthreads();

    // ---- phase B: 16-row MFMA gemm, 4 waves x 2 n-tiles ----
    int wv = tid >> 6;
    int lane = tid & 63;
    int c16 = lane & 15;
    int q = lane >> 4;

    floatx4 acc[2];
    acc[0] = (floatx4){0.f, 0.f, 0.f, 0.f};
    acc[1] = (floatx4){0.f, 0.f, 0.f, 0.f};

    const short8* WH = (const short8*)w2h;
    const short8* WL = (const short8*)w2l;
#pragma unroll
    for (int s = 0; s < 4; ++s) {
        short8 a = *(const short8*)&Albs[c16 * 136 + s * 32 + q * 8];
        int wb = s * 512 + c16 * 4 + q;
#pragma unroll
        for (int i = 0; i < 2; ++i) {
            int nt = wv * 2 + i;
            acc[i] = __builtin_amdgcn_mfma_f32_16x16x32_bf16(a, WH[wb + nt * 64], acc[i], 0, 0, 0);
            acc[i] = __builtin_amdgcn_mfma_f32_16x16x32_bf16(a, WL[wb + nt * 64], acc[i], 0, 0, 0);
        }
    }

    int rbase = row0 + q * 4;
#pragma unroll
    for (int r = 0; r < 4; ++r) {
        int row = rbase + r;
        float dv = dinv[row];
#pragma unroll
        for (int i = 0; i < 2; ++i) {
            int nt = wv * 2 + i;
            tmp2[row * 128 + nt * 16 + c16] = f2bf(acc[i][r] * dv);
        }
    }
}

// ---------------- layer-2 aggregation (standalone) ----------------
__global__ __launch_bounds__(256) void k_agg(const unsigned short* __restrict__ tmp16,
                                             const int* __restrict__ csr,
                                             const int* __restrict__ rowstart,
                                             const float* __restrict__ dinv,
                                             const float* __restrict__ bias,
                                             unsigned short* __restrict__ out16) {
    int node = (blockIdx.x * blockDim.x + threadIdx.x) >> 4;
    int lane = threadIdx.x & 15;
    if (node >= N) return;
    const uint4* t8 = (const uint4*)tmp16;
    float acc[8] = {0.f, 0.f, 0.f, 0.f, 0.f, 0.f, 0.f, 0.f};
    fma8(t8[node * 16 + lane], 1.0f, acc);
    agg_loop(t8, csr, rowstart[node], rowstart[node + 1], lane, acc);

    float di = dinv[node];
    const float4* b4 = (const float4*)bias;
    float4 ba = b4[lane * 2], bb = b4[lane * 2 + 1];
    uint4 o;
    o.x = pack2bf(fmaxf(fmaf(acc[0], di, ba.x), 0.f), fmaxf(fmaf(acc[1], di, ba.y), 0.f));
    o.y = pack2bf(fmaxf(fmaf(acc[2], di, ba.z), 0.f), fmaxf(fmaf(acc[3], di, ba.w), 0.f));
    o.z = pack2bf(fmaxf(fmaf(acc[4], di, bb.x), 0.f), fmaxf(fmaf(acc[5], di, bb.y), 0.f));
    o.w = pack2bf(fmaxf(fmaf(acc[6], di, bb.z), 0.f), fmaxf(fmaf(acc[7], di, bb.w), 0.f));
    ((uint4*)out16)[node * 16 + lane] = o;
}

// ---------------- mean-pool accumulate over bf16 h (batch is sorted) ----------------
__global__ void k_pool(const unsigned short* __restrict__ h16, const int* __restrict__ batch,
                       float* __restrict__ sums) {
    int grp = (blockIdx.x * blockDim.x + threadIdx.x) >> 4;
    int lane = threadIdx.x & 15;
    int base = grp * 64;
    if (base >= N) return;
    int end = (base + 64 < N) ? base + 64 : N;
    float acc[8] = {0.f, 0.f, 0.f, 0.f, 0.f, 0.f, 0.f, 0.f};
    const uint4* h4 = (const uint4*)h16;
    int curb = batch[base];
    for (int i = base; i < end; ++i) {
        int b = batch[i];
        if (b != curb) {
            float* sp = &sums[curb * F + lane * 8];
#pragma unroll
            for (int k = 0; k < 8; ++k) { atomicAdd(sp + k, acc[k]); acc[k] = 0.f; }
            curb = b;
        }
        fma8(h4[i * 16 + lane], 1.0f, acc);
    }
    float* sp = &sums[curb * F + lane * 8];
#pragma unroll
    for (int k = 0; k < 8; ++k) atomicAdd(sp + k, acc[k]);
}

// ---------------- fused fc + head ----------------
__global__ __launch_bounds__(128) void k_fchead(const float* __restrict__ sums,
                                                const float* __restrict__ cnt,
                                                const float* __restrict__ Wfc,
                                                const float* __restrict__ bfc,
                                                const float* __restrict__ Wh,
                                                const float* __restrict__ bh,
                                                float* __restrict__ out) {
    __shared__ float p[128];
    __shared__ float zs[128];
    int g = blockIdx.x, t = threadIdx.x;
    float inv = 1.0f / fmaxf(cnt[g], 1.0f);
    p[t] = sums[g * F + t] * inv;
    __syncthreads();
    float acc = bfc[t];
    for (int k = 0; k < F; ++k) acc = fmaf(p[k], Wfc[k * F + t], acc);
    zs[t] = fmaxf(acc, 0.f);
    __syncthreads();
    if (t < T * 2) {
        int task = t >> 1, c = t & 1;
        float a = bh[task * 2 + c];
        const float* wr = &Wh[task * F * 2 + c];
        for (int h = 0; h < F; ++h) a = fmaf(zs[h], wr[h * 2], a);
        out[task * (G * 2) + g * 2 + c] = a;
    }
}

extern "C" void kernel_launch(void* const* d_in, const int* in_sizes, int n_in,
                              void* d_out, int out_size, void* d_ws, size_t ws_size,
                              hipStream_t stream) {
    const float* x    = (const float*)d_in[0];
    const int*   ei   = (const int*)d_in[1];      // [2,E]: row0=src, row1=dst
    const int*   batch= (const int*)d_in[2];
    const float* W1   = (const float*)d_in[3];
    const float* b1   = (const float*)d_in[4];
    const float* W2   = (const float*)d_in[5];
    const float* b2   = (const float*)d_in[6];
    const float* Wfc  = (const float*)d_in[7];
    const float* bfc  = (const float*)d_in[8];
    const float* Wh   = (const float*)d_in[9];
    const float* bh   = (const float*)d_in[10];
    float* out = (float*)d_out;

    const int* srcp = ei;
    const int* dstp = ei + E;

    char* w = (char*)d_ws;
    auto alloc = [&](size_t bytes) {
        char* p = w;
        w += (bytes + 255) & ~(size_t)255;
        return p;
    };
    unsigned short* tmp16 = (unsigned short*)alloc((size_t)N * F * 2);
    unsigned short* tmp2  = (unsigned short*)alloc((size_t)N * F * 2);
    unsigned short* hbuf16= (unsigned short*)alloc((size_t)N * F * 2);
    int*   csr      = (int*)  alloc((size_t)E * 4);
    unsigned int* staging = (unsigned int*)alloc((size_t)E * 4);
    int*   cnts     = (int*)  alloc((size_t)NCHUNK * NBUCK * 4);
    int*   btot     = (int*)  alloc((size_t)NBUCK * 4);
    int*   bucketbase=(int*)  alloc((size_t)(NBUCK + 1) * 4);
    int*   rowstart = (int*)  alloc((size_t)(N + 1) * 4);
    float* dinv     = (float*)alloc((size_t)N * 4);
    float* sums     = (float*)alloc((size_t)G * F * 4);
    float* cnt      = (float*)alloc((size_t)G * 4);
    unsigned short* w1h = (unsigned short*)alloc((size_t)F * F * 2);
    unsigned short* w1l = (unsigned short*)alloc((size_t)F * F * 2);
    unsigned short* w2h = (unsigned short*)alloc((size_t)F * F * 2);
    unsigned short* w2l = (unsigned short*)alloc((size_t)F * F * 2);

    // fused preamble: wcast W1/W2, cntbs, per-chunk LDS bucket histogram, zero sums
    k_pre<<<PRE_BLKS, 256, 0, stream>>>(W1, W2, w1h, w1l, w2h, w2l,
                                        dstp, cnts, batch, cnt, sums);

    // deterministic radix partition (zero global atomics)
    k_colscan<<<(NBUCK + 255) / 256, 256, 0, stream>>>(cnts, btot);
    k_bucketscan<<<1, 256, 0, stream>>>(btot, bucketbase);
    k_fillb<<<NCHUNK, 256, 0, stream>>>(srcp, dstp, cnts, bucketbase, staging);
    k_passB<<<NBUCK, 256, 0, stream>>>(staging, bucketbase, csr, rowstart, dinv);

    // layer-1 GEMM (dinv-prescaled output)
    k_gemm<false><<<GB1, 256, 0, stream>>>(x, w1h, w1l, dinv, tmp16);

    // fused: layer-1 aggregation + layer-2 GEMM (h1 stays in LDS)
    k_agg1gemm<<<AGB, 256, 0, stream>>>(tmp16, csr, rowstart, dinv, b1, w2h, w2l, tmp2);

    // layer-2 aggregation
    k_agg<<<(N * 16 + 255) / 256, 256, 0, stream>>>(tmp2, csr, rowstart, dinv, b2, hbuf16);

    // pooling
    int ngrp = (N + 63) / 64;
    k_pool<<<(ngrp * 16 + 255) / 256, 256, 0, stream>>>(hbuf16, batch, sums);

    // fc + heads (fused)
    k_fchead<<<G, 128, 0, stream>>>(sums, cnt, Wfc, bfc, Wh, bh, out);
}